// Round 5
// baseline (1862.498 us; speedup 1.0000x reference)
//
#include <hip/hip_runtime.h>

#define D0 8192
#define D1 4096
#define D2 8192
#define NBF 256  // blocks per matrix in full-step passes (= split-K partials)
#define NB1 512  // blocks for the step-1 W0-only pass

// ---------------------------------------------------------------------------
// Fused per-matrix pass, 512 threads/block, block owns RPB rows.
//   e[j] = c[j] - tanh(W[j,:] . x)      (row dot, 1 barrier per batch)
//   ACC: acc[cols] += e[j] * W[j,:]     (register slice -> partial per block)
//   ERR: errsum += e[j]^2 -> atomicAdd(out); stores nothing else
//   WE : store e[j] (only the W1 pass needs it; e0 is dead in full steps)
// Batch = 4 float4/thread (W0: 2 rows, W1: 1 row). Triple-buffer ring gives
// a 2-batch load lookahead (128 B/thread in flight). Fully unrolled so all
// buffer indices are compile-time (no scratch). Footprint ~100 VGPR -> fits
// the 128-reg cap of __launch_bounds__(512,4): 16 waves/CU, no spill.
// ---------------------------------------------------------------------------
template <int K, int RPB, bool ACC, bool ERR, bool WE>
__device__ __forceinline__ void fused_body(
    const float* __restrict__ W, const float* __restrict__ x,
    const float* __restrict__ c, float* __restrict__ e,
    float* __restrict__ part, int bid, float* __restrict__ out) {
  constexpr int F4 = K / 2048;     // float4 per thread per row (W0:2, W1:4)
  constexpr int R = 4 / F4;        // rows per batch (W0:2, W1:1)
  constexpr int NBATCH = RPB / R;  // 8 or 16
  static_assert(NBATCH >= 3, "ring schedule needs >=3 batches");

  const int t = threadIdx.x;
  const int lane = t & 63;
  const int wave = t >> 6;
  const int r0 = bid * RPB;

  __shared__ float red[2][R][8];

  float4 xr[F4];
#pragma unroll
  for (int i = 0; i < F4; ++i)
    xr[i] = *reinterpret_cast<const float4*>(&x[i * 2048 + t * 4]);

  float4 acc[F4];
#pragma unroll
  for (int i = 0; i < F4; ++i) acc[i] = make_float4(0.f, 0.f, 0.f, 0.f);

  float errsum = 0.f;
  float4 b0[4], b1[4], b2[4];  // ring buffers, statically indexed

  auto load = [&](float4* buf, int b) {
    const float* wp = W + (size_t)(r0 + b * R) * K;
#pragma unroll
    for (int r = 0; r < R; ++r)
#pragma unroll
      for (int i = 0; i < F4; ++i)
        buf[r * F4 + i] = *reinterpret_cast<const float4*>(
            &wp[(size_t)r * K + i * 2048 + t * 4]);
  };

  auto proc = [&](float4* buf, int b, int par) {
    const int j0 = r0 + b * R;
    float dp[R];
#pragma unroll
    for (int r = 0; r < R; ++r) {
      float s = 0.f;
#pragma unroll
      for (int i = 0; i < F4; ++i) {
        const float4 w = buf[r * F4 + i];
        s += w.x * xr[i].x + w.y * xr[i].y + w.z * xr[i].z + w.w * xr[i].w;
      }
      dp[r] = s;
    }
#pragma unroll
    for (int off = 32; off; off >>= 1)
#pragma unroll
      for (int r = 0; r < R; ++r) dp[r] += __shfl_down(dp[r], off, 64);
    if (lane == 0)
#pragma unroll
      for (int r = 0; r < R; ++r) red[par][r][wave] = dp[r];
    __syncthreads();  // also orders the parity-LDS reuse (distance-2, safe)
    float ej[R];
#pragma unroll
    for (int r = 0; r < R; ++r) {
      float s = red[par][r][0];
#pragma unroll
      for (int w = 1; w < 8; ++w) s += red[par][r][w];
      ej[r] = c[j0 + r] - tanhf(s);
    }
    if constexpr (WE) {
      if (t == 0) {
#pragma unroll
        for (int r = 0; r < R; ++r) e[j0 + r] = ej[r];
      }
    }
    if constexpr (ERR) {
      if (t == 0) {
#pragma unroll
        for (int r = 0; r < R; ++r) errsum += ej[r] * ej[r];
      }
    }
    if constexpr (ACC) {
#pragma unroll
      for (int r = 0; r < R; ++r)
#pragma unroll
        for (int i = 0; i < F4; ++i) {
          acc[i].x += ej[r] * buf[r * F4 + i].x;
          acc[i].y += ej[r] * buf[r * F4 + i].y;
          acc[i].z += ej[r] * buf[r * F4 + i].z;
          acc[i].w += ej[r] * buf[r * F4 + i].w;
        }
    }
  };

  // ring schedule: batch k lives in buffer k%3; 2 batches always in flight.
  load(b0, 0);
  load(b1, 1);
  load(b2, 2);
#pragma unroll
  for (int b = 0; b < NBATCH; b += 3) {
    proc(b0, b, b & 1);
    if (b + 3 < NBATCH) load(b0, b + 3);
    if (b + 1 < NBATCH) {
      proc(b1, b + 1, (b + 1) & 1);
      if (b + 4 < NBATCH) load(b1, b + 4);
    }
    if (b + 2 < NBATCH) {
      proc(b2, b + 2, (b + 2) & 1);
      if (b + 5 < NBATCH) load(b2, b + 5);
    }
  }

  if constexpr (ACC) {
    float* pp = part + (size_t)bid * K;
#pragma unroll
    for (int i = 0; i < F4; ++i)
      *reinterpret_cast<float4*>(&pp[i * 2048 + t * 4]) = acc[i];
  }
  if constexpr (ERR) {
    if (t == 0) atomicAdd(out, errsum);
  }
}

// ---- step 1: W0 pass only, whole machine (512 blocks x 16 rows) -----------
__global__ __launch_bounds__(512, 4) void pass_w0_kernel(
    const float* __restrict__ W0_, const float* __restrict__ x1_,
    const float* __restrict__ x0_, float* __restrict__ t1p_) {
  fused_body<D1, D0 / NB1, true, false, false>(W0_, x1_, x0_, nullptr, t1p_,
                                               blockIdx.x, nullptr);
}

// ---- full step: W0 pass (blocks 0..255) || W1 pass (blocks 256..511) ------
__global__ __launch_bounds__(512, 4) void step_full_kernel(
    const float* __restrict__ W0_, const float* __restrict__ W1_,
    const float* __restrict__ x0_, const float* __restrict__ x1_,
    const float* __restrict__ x2_, float* __restrict__ e1_,
    float* __restrict__ t1p_, float* __restrict__ t2p_) {
  if (blockIdx.x < NBF) {
    // e0 is dead in full steps (only t1 partials are consumed) -> no store
    fused_body<D1, D0 / NBF, true, false, false>(W0_, x1_, x0_, nullptr, t1p_,
                                                 blockIdx.x, nullptr);
  } else {
    fused_body<D2, D1 / NBF, true, false, true>(W1_, x2_, x1_, e1_, t2p_,
                                                blockIdx.x - NBF, nullptr);
  }
}

// ---- step 10: error-only passes for both matrices -------------------------
__global__ __launch_bounds__(512, 4) void step_err_kernel(
    const float* __restrict__ W0_, const float* __restrict__ W1_,
    const float* __restrict__ x0_, const float* __restrict__ x1_,
    const float* __restrict__ x2_, float* __restrict__ out) {
  if (blockIdx.x < NBF) {
    fused_body<D1, D0 / NBF, false, true, false>(W0_, x1_, x0_, nullptr,
                                                 nullptr, blockIdx.x, out);
  } else {
    fused_body<D2, D1 / NBF, false, true, false>(W1_, x2_, x1_, nullptr,
                                                 nullptr, blockIdx.x - NBF,
                                                 out);
  }
}

// ---------------------------------------------------------------------------
// Update: reduce n split-K partials (4 p-lanes x n/4 deep + LDS combine) and
// apply x' = tanh(x + 0.01*clip(-e_self + t, -1, 1)).
// Block owns 64 consecutive elements of concat [t1(4096) | t2(8192)].
// grid 192, n=256 = full step; grid 64, n=512 = step-1 (x2 stays 0).
// ---------------------------------------------------------------------------
__global__ __launch_bounds__(256) void update_kernel(
    float* __restrict__ x1, const float* __restrict__ e1,
    const float* __restrict__ t1p, float* __restrict__ x2,
    const float* __restrict__ t2p, int n) {
  const int t = threadIdx.x;
  const int cl = t & 63;
  const int pl = t >> 6;
  const int base = blockIdx.x * 64;
  const int nd4 = n >> 2;
  __shared__ float red[4][64];
  float s = 0.f;
  if (base < D1) {
    const float* p = t1p + base + cl;
    for (int k = pl * nd4; k < (pl + 1) * nd4; ++k) s += p[(size_t)k * D1];
  } else {
    const float* p = t2p + (base - D1) + cl;
    for (int k = pl * nd4; k < (pl + 1) * nd4; ++k) s += p[(size_t)k * D2];
  }
  red[pl][cl] = s;
  __syncthreads();
  if (pl == 0) {
    const float ts = red[0][cl] + red[1][cl] + red[2][cl] + red[3][cl];
    if (base < D1) {
      const int i = base + cl;
      const float g = fminf(fmaxf(-e1[i] + ts, -1.f), 1.f);
      x1[i] = tanhf(x1[i] + 0.01f * g);
    } else {
      const int i = base - D1 + cl;
      const float g = fminf(fmaxf(-x2[i] + ts, -1.f), 1.f);
      x2[i] = tanhf(x2[i] + 0.01f * g);
    }
  }
}

// ---- init: x1=x2=0, e1=0, out=0 (ws/out arrive poisoned 0xAA) -------------
__global__ __launch_bounds__(256) void init_kernel(float* __restrict__ x1,
                                                   float* __restrict__ x2,
                                                   float* __restrict__ e1,
                                                   float* __restrict__ out) {
  int i = blockIdx.x * 256 + threadIdx.x;
  if (i == 0) out[0] = 0.f;
  if (i < D1) {
    x1[i] = 0.f;
    e1[i] = 0.f;
  }
  if (i < D2) x2[i] = 0.f;
}

// ---- sum(x^2) for the top layer (e2 = x2) ---------------------------------
__global__ __launch_bounds__(256) void sumsq_kernel(const float* __restrict__ x,
                                                    int n,
                                                    float* __restrict__ out) {
  float s = 0.f;
  for (int i = blockIdx.x * 256 + threadIdx.x; i < n; i += gridDim.x * 256)
    s += x[i] * x[i];
#pragma unroll
  for (int off = 32; off; off >>= 1) s += __shfl_down(s, off, 64);
  if ((threadIdx.x & 63) == 0) atomicAdd(out, s);
}

extern "C" void kernel_launch(void* const* d_in, const int* in_sizes, int n_in,
                              void* d_out, int out_size, void* d_ws,
                              size_t ws_size, hipStream_t stream) {
  const float* x0 = (const float*)d_in[0];  // 8192
  const float* W0 = (const float*)d_in[1];  // 8192x4096 row-major
  const float* W1 = (const float*)d_in[2];  // 4096x8192 row-major
  // d_in[3] = steps (fixed at 10; launch count must be static)
  float* out = (float*)d_out;

  float* ws = (float*)d_ws;
  float* x1 = ws;                       // 4096
  float* x2 = x1 + D1;                  // 8192
  float* e1 = x2 + D2;                  // 4096
  float* t1p = e1 + D1;                 // NB1 x 4096  (8 MB, step-1 uses 512)
  float* t2p = t1p + (size_t)NB1 * D1;  // NBF x 8192  (8 MB)

  const dim3 B512(512), B256(256);

  // init + step 1: x1=x2=0 => e0=x0 (dot=0, tanh(0)=0), e1=0, t2=0.
  // W0 pass still needed for t1 = e0@W0; x2 stays 0 (update covers t1 only).
  init_kernel<<<D0 / 256, B256, 0, stream>>>(x1, x2, e1, out);
  pass_w0_kernel<<<NB1, B512, 0, stream>>>(W0, x1, x0, t1p);
  update_kernel<<<D1 / 64, B256, 0, stream>>>(x1, e1, t1p, x2, t2p, NB1);

  // steps 2..9: both matrix passes in ONE launch, each W read exactly once.
  for (int s = 2; s <= 9; ++s) {
    step_full_kernel<<<2 * NBF, B512, 0, stream>>>(W0, W1, x0, x1, x2, e1,
                                                   t1p, t2p);
    update_kernel<<<(D1 + D2) / 64, B256, 0, stream>>>(x1, e1, t1p, x2, t2p,
                                                       NBF);
  }

  // step 10: only the errors are observable (final state update is dead).
  step_err_kernel<<<2 * NBF, B512, 0, stream>>>(W0, W1, x0, x1, x2, out);
  sumsq_kernel<<<8, B256, 0, stream>>>(x2, D2, out);  // e2 = x2
}

// Round 7
// 850.001 us; speedup vs baseline: 2.1912x; 2.1912x over previous
//
#include <hip/hip_runtime.h>

#define D0 8192
#define D1 4096
#define D2 8192
#define NBF 256    // blocks per matrix in full-step passes (= split-K partials)
#define NB1 512    // blocks for the step-1 W0-only pass
#define NTHR 1024  // threads per fused block
#define TILE 8192  // floats per LDS tile (32 KB): W0 = 2 rows, W1 = 1 row

// Direct global->LDS (no VGPR round-trip). Per-lane global src; HW writes
// wave-uniform LDS base + lane*16 (passing the per-thread linear address is
// equivalent: readfirstlane(base + t*16) = base + wave*1024).
__device__ __forceinline__ void gload_lds16(const float* gsrc, float* ldst) {
  __builtin_amdgcn_global_load_lds(
      (const __attribute__((address_space(1))) void*)gsrc,
      (__attribute__((address_space(3))) void*)ldst, 16, 0, 0);
}

// ---------------------------------------------------------------------------
// Fused per-matrix pass, LDS-staged. Block owns RPB rows.
//   e[j] = c[j] - tanh(W[j,:] . x)     (row dot, block reduce)
//   ACC: acc[cols] += e[j] * W[j,:]    (tiny register slice -> block partial)
//   ERR: errsum += e[j]^2 -> atomicAdd(out)
//   WE : store e[j] (only W1's e1 is consumed; e0 is dead in full steps)
// Double-buffered 32KB tiles; barrier A = __syncthreads (drains vmcnt: tile
// ready + old buffer free); barrier B = raw lgkmcnt(0)+s_barrier so the
// prefetch issued after A stays in flight across B.
// Register footprint ~40 VGPR: xr/acc are 1 (W0) or 2 (W1) float4 each.
// ---------------------------------------------------------------------------
template <int K, int RPB, bool ACC, bool ERR, bool WE>
__device__ __forceinline__ void fused_body(
    const float* __restrict__ W, const float* __restrict__ x,
    const float* __restrict__ c, float* __restrict__ e,
    float* __restrict__ part, int bid, float* __restrict__ out,
    float (&lds)[2][TILE], float (&red)[2][16]) {
  constexpr int RT = TILE / K;        // rows per tile: W0 2, W1 1
  constexpr int NT = RPB / RT;        // tiles per block (8 or 16)
  constexpr int F4 = K / (NTHR * 4);  // float4 per thread per row: W0 1, W1 2
  static_assert(RPB % RT == 0 && NT >= 2, "");

  const int t = threadIdx.x;
  const int lane = t & 63;
  const int r0 = bid * RPB;

  float4 xr[F4];
#pragma unroll
  for (int i = 0; i < F4; ++i)
    xr[i] = *reinterpret_cast<const float4*>(&x[i * 4096 + t * 4]);

  float4 acc[F4];
#pragma unroll
  for (int i = 0; i < F4; ++i) acc[i] = make_float4(0.f, 0.f, 0.f, 0.f);

  float errsum = 0.f;

  auto stage = [&](int buf, int tb) {
    const float* gp = W + (size_t)(r0 + tb * RT) * K;
#pragma unroll
    for (int s = 0; s < TILE / (NTHR * 4); ++s)  // 2 sweeps x 16KB
      gload_lds16(gp + s * (NTHR * 4) + t * 4,
                  &lds[buf][s * (NTHR * 4) + t * 4]);
  };

  stage(0, 0);
#pragma unroll 2
  for (int b = 0; b < NT; ++b) {
    const int buf = b & 1;
    // barrier A: compiler emits s_waitcnt vmcnt(0) lgkmcnt(0) + s_barrier.
    // vmcnt(0) IS the "tile b ready" wait; also fences buf^1 for reuse.
    __syncthreads();
    if (b + 1 < NT) stage(buf ^ 1, b + 1);  // in flight across barrier B

    // ---- dot phase (reads LDS tile) ----
    float dp[RT];
#pragma unroll
    for (int r = 0; r < RT; ++r) {
      float s = 0.f;
#pragma unroll
      for (int i = 0; i < F4; ++i) {
        const float4 w = *reinterpret_cast<const float4*>(
            &lds[buf][r * K + i * 4096 + t * 4]);
        s += w.x * xr[i].x + w.y * xr[i].y + w.z * xr[i].z + w.w * xr[i].w;
      }
      dp[r] = s;
    }
#pragma unroll
    for (int off = 32; off; off >>= 1)
#pragma unroll
      for (int r = 0; r < RT; ++r) dp[r] += __shfl_down(dp[r], off, 64);
    if (lane == 0)
#pragma unroll
      for (int r = 0; r < RT; ++r) red[r][t >> 6] = dp[r];

    // barrier B: LDS-only fence; prefetch vmcnt stays outstanding.
    asm volatile("s_waitcnt lgkmcnt(0)\n\ts_barrier" ::: "memory");

    // ---- e + accumulate phase ----
    const int j0 = r0 + b * RT;
    float ej[RT];
#pragma unroll
    for (int r = 0; r < RT; ++r) {
      float s = 0.f;
#pragma unroll
      for (int w = 0; w < 16; ++w) s += red[r][w];
      ej[r] = c[j0 + r] - tanhf(s);
    }
    if (t == 0) {
      if constexpr (WE) {
#pragma unroll
        for (int r = 0; r < RT; ++r) e[j0 + r] = ej[r];
      }
      if constexpr (ERR) {
#pragma unroll
        for (int r = 0; r < RT; ++r) errsum += ej[r] * ej[r];
      }
    }
    if constexpr (ACC) {
#pragma unroll
      for (int r = 0; r < RT; ++r)
#pragma unroll
        for (int i = 0; i < F4; ++i) {
          const float4 w = *reinterpret_cast<const float4*>(
              &lds[buf][r * K + i * 4096 + t * 4]);
          acc[i].x += ej[r] * w.x;
          acc[i].y += ej[r] * w.y;
          acc[i].z += ej[r] * w.z;
          acc[i].w += ej[r] * w.w;
        }
    }
  }

  if constexpr (ACC) {
#pragma unroll
    for (int i = 0; i < F4; ++i)
      *reinterpret_cast<float4*>(&part[(size_t)bid * K + i * 4096 + t * 4]) =
          acc[i];
  }
  if constexpr (ERR) {
    if (t == 0) atomicAdd(out, errsum);
  }
}

// ---- step 1: W0 pass only, whole machine (512 blocks x 16 rows) -----------
__global__ __launch_bounds__(NTHR) void pass_w0_kernel(
    const float* __restrict__ W0_, const float* __restrict__ x1_,
    const float* __restrict__ x0_, float* __restrict__ t1p_) {
  __shared__ float lds[2][TILE];
  __shared__ float red[2][16];
  fused_body<D1, D0 / NB1, true, false, false>(W0_, x1_, x0_, nullptr, t1p_,
                                               blockIdx.x, nullptr, lds, red);
}

// ---- full step: W0 pass (blocks 0..255) || W1 pass (blocks 256..511) ------
__global__ __launch_bounds__(NTHR) void step_full_kernel(
    const float* __restrict__ W0_, const float* __restrict__ W1_,
    const float* __restrict__ x0_, const float* __restrict__ x1_,
    const float* __restrict__ x2_, float* __restrict__ e1_,
    float* __restrict__ t1p_, float* __restrict__ t2p_) {
  __shared__ float lds[2][TILE];
  __shared__ float red[2][16];
  if (blockIdx.x < NBF) {
    fused_body<D1, D0 / NBF, true, false, false>(
        W0_, x1_, x0_, nullptr, t1p_, blockIdx.x, nullptr, lds, red);
  } else {
    fused_body<D2, D1 / NBF, true, false, true>(
        W1_, x2_, x1_, e1_, t2p_, blockIdx.x - NBF, nullptr, lds, red);
  }
}

// ---- step 10: error-only passes for both matrices -------------------------
__global__ __launch_bounds__(NTHR) void step_err_kernel(
    const float* __restrict__ W0_, const float* __restrict__ W1_,
    const float* __restrict__ x0_, const float* __restrict__ x1_,
    const float* __restrict__ x2_, float* __restrict__ out) {
  __shared__ float lds[2][TILE];
  __shared__ float red[2][16];
  if (blockIdx.x < NBF) {
    fused_body<D1, D0 / NBF, false, true, false>(
        W0_, x1_, x0_, nullptr, nullptr, blockIdx.x, out, lds, red);
  } else {
    fused_body<D2, D1 / NBF, false, true, false>(
        W1_, x2_, x1_, nullptr, nullptr, blockIdx.x - NBF, out, lds, red);
  }
}

// ---------------------------------------------------------------------------
// Update: reduce n split-K partials (4 p-lanes x n/4 deep + LDS combine) and
// apply x' = tanh(x + 0.01*clip(-e_self + t, -1, 1)).
// Block owns 64 consecutive elements of concat [t1(4096) | t2(8192)].
// grid 192, n=256 = full step; grid 64, n=512 = step-1 (x2 stays 0).
// ---------------------------------------------------------------------------
__global__ __launch_bounds__(256) void update_kernel(
    float* __restrict__ x1, const float* __restrict__ e1,
    const float* __restrict__ t1p, float* __restrict__ x2,
    const float* __restrict__ t2p, int n) {
  const int t = threadIdx.x;
  const int cl = t & 63;
  const int pl = t >> 6;
  const int base = blockIdx.x * 64;
  const int nd4 = n >> 2;
  __shared__ float red[4][64];
  float s = 0.f;
  if (base < D1) {
    const float* p = t1p + base + cl;
    for (int k = pl * nd4; k < (pl + 1) * nd4; ++k) s += p[(size_t)k * D1];
  } else {
    const float* p = t2p + (base - D1) + cl;
    for (int k = pl * nd4; k < (pl + 1) * nd4; ++k) s += p[(size_t)k * D2];
  }
  red[pl][cl] = s;
  __syncthreads();
  if (pl == 0) {
    const float ts = red[0][cl] + red[1][cl] + red[2][cl] + red[3][cl];
    if (base < D1) {
      const int i = base + cl;
      const float g = fminf(fmaxf(-e1[i] + ts, -1.f), 1.f);
      x1[i] = tanhf(x1[i] + 0.01f * g);
    } else {
      const int i = base - D1 + cl;
      const float g = fminf(fmaxf(-x2[i] + ts, -1.f), 1.f);
      x2[i] = tanhf(x2[i] + 0.01f * g);
    }
  }
}

// ---- init: x1=x2=0, e1=0, out=0 (ws/out arrive poisoned 0xAA) -------------
__global__ __launch_bounds__(256) void init_kernel(float* __restrict__ x1,
                                                   float* __restrict__ x2,
                                                   float* __restrict__ e1,
                                                   float* __restrict__ out) {
  int i = blockIdx.x * 256 + threadIdx.x;
  if (i == 0) out[0] = 0.f;
  if (i < D1) {
    x1[i] = 0.f;
    e1[i] = 0.f;
  }
  if (i < D2) x2[i] = 0.f;
}

// ---- sum(x^2) for the top layer (e2 = x2) ---------------------------------
__global__ __launch_bounds__(256) void sumsq_kernel(const float* __restrict__ x,
                                                    int n,
                                                    float* __restrict__ out) {
  float s = 0.f;
  for (int i = blockIdx.x * 256 + threadIdx.x; i < n; i += gridDim.x * 256)
    s += x[i] * x[i];
#pragma unroll
  for (int off = 32; off; off >>= 1) s += __shfl_down(s, off, 64);
  if ((threadIdx.x & 63) == 0) atomicAdd(out, s);
}

extern "C" void kernel_launch(void* const* d_in, const int* in_sizes, int n_in,
                              void* d_out, int out_size, void* d_ws,
                              size_t ws_size, hipStream_t stream) {
  const float* x0 = (const float*)d_in[0];  // 8192
  const float* W0 = (const float*)d_in[1];  // 8192x4096 row-major
  const float* W1 = (const float*)d_in[2];  // 4096x8192 row-major
  // d_in[3] = steps (fixed at 10; launch count must be static)
  float* out = (float*)d_out;

  float* ws = (float*)d_ws;
  float* x1 = ws;                       // 4096
  float* x2 = x1 + D1;                  // 8192
  float* e1 = x2 + D2;                  // 4096
  float* t1p = e1 + D1;                 // NB1 x 4096  (8 MB; step-1 uses 512)
  float* t2p = t1p + (size_t)NB1 * D1;  // NBF x 8192  (8 MB)

  const dim3 BT(NTHR), B256(256);

  // init + step 1: x1=x2=0 => e0=x0 (dot=0, tanh(0)=0), e1=0, t2=0.
  // W0 pass still needed for t1 = e0@W0; x2 stays 0 (update covers t1 only).
  init_kernel<<<D0 / 256, B256, 0, stream>>>(x1, x2, e1, out);
  pass_w0_kernel<<<NB1, BT, 0, stream>>>(W0, x1, x0, t1p);
  update_kernel<<<D1 / 64, B256, 0, stream>>>(x1, e1, t1p, x2, t2p, NB1);

  // steps 2..9: both matrix passes in ONE launch, each W read exactly once.
  for (int s = 2; s <= 9; ++s) {
    step_full_kernel<<<2 * NBF, BT, 0, stream>>>(W0, W1, x0, x1, x2, e1, t1p,
                                                 t2p);
    update_kernel<<<(D1 + D2) / 64, B256, 0, stream>>>(x1, e1, t1p, x2, t2p,
                                                       NBF);
  }

  // step 10: only the errors are observable (final state update is dead).
  step_err_kernel<<<2 * NBF, BT, 0, stream>>>(W0, W1, x0, x1, x2, out);
  sumsq_kernel<<<8, B256, 0, stream>>>(x2, D2, out);  // e2 = x2
}